// Round 2
// baseline (105.731 us; speedup 1.0000x reference)
//
#include <hip/hip_runtime.h>
#include <math.h>
#include <stdint.h>

// SemiConv2d tropical conv: out = max_{ic,kh,kw} min(x_pad, K). f16-packed.
// R15: OC-GROUP SHARING (4 oc per block). Post-mortem of R14: halving loads
// AND iterations moved total only -2.8us => per-wave load volume is NOT the
// binding constraint; the conserved quantity across R2-R14 is the 32x
// re-read of every xq row (one block per oc). R15: one dwordx2 row load
// feeds FOUR accumulators (k's in SGPRs via pkmin_vs "s" operand), waves
// 18432->4608, dense L2 bytes 906->226MB (~6.5us), VALU ~9us => main
// ~10-14us even with NO early exit. Exit kept on group threshold gmax =
// max of 12 k's/row (sorted desc; exact: every remaining k <= gmax[next],
// f16 cvt monotone), fires ~row 83 (order stats) => minor extra ~13%.
// Setup fused into ONE launch (xq pack + table build) to cut a launch gap.
// Predict: total 98.7 -> ~72-78us if main was the cost; if >=93us, main
// was already ~10-15us and remaining budget is harness fill (44us
// re-poison) + setup + launch gaps -> next round attacks fixed costs.

#define HH 96
#define WW 96
#define CIN 32
#define OCN 32
#define XQ_ROWS 98
#define XQ_W 48
#define XQ_SLICE (XQ_ROWS * XQ_W)              // uint2 units per (n,ic) slice
#define XQ_TOTAL (256 * XQ_SLICE)              // uint2 elements
#define XQB (XQ_TOTAL / 256)                   // 4704 xq-pack blocks
#define NROW 96                                 // row-entries per oc-group
#define NOCG 8                                  // 8 groups x 4 oc
#define TBLG_BYTES ((size_t)NOCG * NROW * 64)  // 4 uint4 per entry
#define WS_NEED ((size_t)XQ_TOTAL * 8 + TBLG_BYTES)
#define NEGH2 0xFC00FC00u

typedef _Float16 h2 __attribute__((ext_vector_type(2)));
typedef uint32_t u2a4 __attribute__((ext_vector_type(2), aligned(4)));

__device__ __forceinline__ uint32_t pkmin_vs(uint32_t x, uint32_t k) {
    uint32_t d;
    asm("v_pk_min_f16 %0, %1, %2" : "=v"(d) : "v"(x), "s"(k));
    return d;
}
__device__ __forceinline__ uint32_t pkmin_vv(uint32_t a, uint32_t b) {
    uint32_t d;
    asm("v_pk_min_f16 %0, %1, %2" : "=v"(d) : "v"(a), "v"(b));
    return d;
}
__device__ __forceinline__ uint32_t pkmax(uint32_t a, uint32_t b) {
    uint32_t d;
    asm("v_pk_max_f16 %0, %1, %2" : "=v"(d) : "v"(a), "v"(b));
    return d;
}
__device__ __forceinline__ uint32_t packh2(float lo, float hi) {
    h2 p = {(_Float16)lo, (_Float16)hi};
    return __builtin_bit_cast(uint32_t, p);
}

// Fused setup. Blocks [0,XQB): pack x into xq
//   xq[(s*98 + rowpad)*48 + j] = 4xf16 (x[2j-1],x[2j] | x[2j+1],x[2j+2]), s=n*32+ic
// Blocks [XQB, XQB+8): per-ocg row table, sorted by group-rowmax desc.
//   entry(4xuint4): {k00,k01,k02,k10 | k11,k12,k20,k21 | k22,k30,k31,k32 |
//                    byte_off, gmax_dup, 0, 0}  (kXY = oc X in group, kw Y, f16 dup)
__global__ __launch_bounds__(256) void setup_all(const float* __restrict__ x,
                                                 const float* __restrict__ kk,
                                                 uint2* __restrict__ xq,
                                                 uint4* __restrict__ tblg) {
    __shared__ float rs[NROW];
    const int bb = blockIdx.x;
    if (bb < XQB) {
        int idx = bb * 256 + threadIdx.x;       // over 256*98*48 = 1,204,224
        int j  = idx % XQ_W;
        int t  = idx / XQ_W;
        int hp = t % XQ_ROWS;
        int s  = t / XQ_ROWS;
        int h  = hp - 1;
        bool hv = (h >= 0) && (h < HH);
        const float* row = x + ((size_t)s * HH + (hv ? h : 0)) * WW;
        float a = (hv && j > 0)        ? row[2 * j - 1] : -INFINITY;
        float b = hv                   ? row[2 * j]     : -INFINITY;
        float c = hv                   ? row[2 * j + 1] : -INFINITY;
        float d = (hv && j < XQ_W - 1) ? row[2 * j + 2] : -INFINITY;
        uint2 v;
        v.x = packh2(a, b);
        v.y = packh2(c, d);
        xq[idx] = v;
        return;
    }
    // ---- table path ----
    const int ocg = bb - XQB;
    const int t   = threadIdx.x;                // rows handled by t < 96
    float kv[12];
    float gm = -INFINITY;
    if (t < NROW) {
        const int ic = t / 3, dh = t - 3 * ic;
#pragma unroll
        for (int o = 0; o < 4; ++o) {
            const float* kp = kk + ((size_t)((ocg * 4 + o) * CIN + ic) * 3 + dh) * 3;
#pragma unroll
            for (int w = 0; w < 3; ++w) {
                float v = kp[w];
                kv[o * 3 + w] = v;
                gm = fmaxf(gm, v);
            }
        }
        rs[t] = gm;
    }
    __syncthreads();
    if (t < NROW) {
        int rank = 0;
        for (int s = 0; s < NROW; ++s) {
            float v = rs[s];
            rank += (v > gm) || (v == gm && s < t);
        }
        const int ic = t / 3, dh = t - 3 * ic;
        uint32_t off = (uint32_t)(ic * XQ_ROWS + dh) * (XQ_W * 8);
        uint4* e = tblg + ((size_t)ocg * NROW + rank) * 4;
        e[0] = make_uint4(packh2(kv[0], kv[0]),  packh2(kv[1], kv[1]),
                          packh2(kv[2], kv[2]),  packh2(kv[3], kv[3]));
        e[1] = make_uint4(packh2(kv[4], kv[4]),  packh2(kv[5], kv[5]),
                          packh2(kv[6], kv[6]),  packh2(kv[7], kv[7]));
        e[2] = make_uint4(packh2(kv[8], kv[8]),  packh2(kv[9], kv[9]),
                          packh2(kv[10], kv[10]), packh2(kv[11], kv[11]));
        e[3] = make_uint4(off, packh2(gm, gm), 0u, 0u);
    }
}

// One row-load feeds 4 oc accumulators.
__global__ __launch_bounds__(192, 8) void semiconv_g4(const char* __restrict__ xqb,
                                                      const uint4* __restrict__ tblg,
                                                      float* __restrict__ out) {
    const int tid = threadIdx.x;
    const int jj = tid % 48;          // w-pair 0..47
    const int hr = tid / 48;          // 0..3
    const int b  = blockIdx.x;
    const int hp = b % 24;            // hp FASTEST -> XCD spread + L2 locality
    const int t  = b / 24;
    const int ocg = t & 7;
    const int n   = t >> 3;
    const int h  = hp * 4 + hr;       // one output row per thread (2 w)

    const char* xb = xqb + (size_t)n * CIN * XQ_SLICE * 8
                         + (size_t)(h * XQ_W + jj) * 8;
    const uint4* tb = tblg + (size_t)ocg * NROW * 4;

    uint32_t a0 = NEGH2, a1 = NEGH2, a2 = NEGH2, a3 = NEGH2;
    uint4 eA0 = tb[0], eB0 = tb[1], eC0 = tb[2], eD0 = tb[3];
    uint4 eA1 = tb[4], eB1 = tb[5], eC1 = tb[6], eD1 = tb[7];

    for (int c = 0; c < NROW / 2; ++c) {
        uint4 fA0, fB0, fC0, fD0, fA1, fB1, fC1, fD1;
        if (c < NROW / 2 - 1) {       // prefetch next row-pair (uniform -> s_load)
            const uint4* nb = tb + 8 * (c + 1);
            fA0 = nb[0]; fB0 = nb[1]; fC0 = nb[2]; fD0 = nb[3];
            fA1 = nb[4]; fB1 = nb[5]; fC1 = nb[6]; fD1 = nb[7];
        }
        u2a4 q0 = *(const u2a4*)(xb + eD0.x);
        u2a4 q1 = *(const u2a4*)(xb + eD1.x);
        uint32_t v01 = __builtin_amdgcn_alignbit(q0.y, q0.x, 16);
        uint32_t v11 = __builtin_amdgcn_alignbit(q1.y, q1.x, 16);
        // row 0 -> 4 oc
        a0 = pkmax(a0, pkmax(pkmax(pkmin_vs(q0.x, eA0.x), pkmin_vs(v01, eA0.y)),
                             pkmin_vs(q0.y, eA0.z)));
        a1 = pkmax(a1, pkmax(pkmax(pkmin_vs(q0.x, eA0.w), pkmin_vs(v01, eB0.x)),
                             pkmin_vs(q0.y, eB0.y)));
        a2 = pkmax(a2, pkmax(pkmax(pkmin_vs(q0.x, eB0.z), pkmin_vs(v01, eB0.w)),
                             pkmin_vs(q0.y, eC0.x)));
        a3 = pkmax(a3, pkmax(pkmax(pkmin_vs(q0.x, eC0.y), pkmin_vs(v01, eC0.z)),
                             pkmin_vs(q0.y, eC0.w)));
        // row 1 -> 4 oc
        a0 = pkmax(a0, pkmax(pkmax(pkmin_vs(q1.x, eA1.x), pkmin_vs(v11, eA1.y)),
                             pkmin_vs(q1.y, eA1.z)));
        a1 = pkmax(a1, pkmax(pkmax(pkmin_vs(q1.x, eA1.w), pkmin_vs(v11, eB1.x)),
                             pkmin_vs(q1.y, eB1.y)));
        a2 = pkmax(a2, pkmax(pkmax(pkmin_vs(q1.x, eB1.z), pkmin_vs(v11, eB1.w)),
                             pkmin_vs(q1.y, eC1.x)));
        a3 = pkmax(a3, pkmax(pkmax(pkmin_vs(q1.x, eC1.y), pkmin_vs(v11, eC1.z)),
                             pkmin_vs(q1.y, eC1.w)));

        if (c < NROW / 2 - 1) {
            // done iff min over 4 accs, both halves >= next gmax (max of remaining)
            uint32_t mn = pkmin_vv(pkmin_vv(a0, a1), pkmin_vv(a2, a3));
            mn = pkmin_vv(mn, __builtin_amdgcn_alignbit(mn, mn, 16));
            h2 aa = __builtin_bit_cast(h2, mn);
            h2 kn = __builtin_bit_cast(h2, fD0.y);
            if (__all((float)aa.x >= (float)kn.x)) break;
            eA0 = fA0; eB0 = fB0; eC0 = fC0; eD0 = fD0;
            eA1 = fA1; eB1 = fB1; eC1 = fC1; eD1 = fD1;
        }
    }

    float* ob = out + (((size_t)(n * OCN + ocg * 4)) * HH + h) * WW + 2 * jj;
    h2 r0 = __builtin_bit_cast(h2, a0);
    h2 r1 = __builtin_bit_cast(h2, a1);
    h2 r2 = __builtin_bit_cast(h2, a2);
    h2 r3 = __builtin_bit_cast(h2, a3);
    *(float2*)(ob)                  = make_float2((float)r0.x, (float)r0.y);
    *(float2*)(ob + HH * WW)        = make_float2((float)r1.x, (float)r1.y);
    *(float2*)(ob + 2 * HH * WW)    = make_float2((float)r2.x, (float)r2.y);
    *(float2*)(ob + 3 * HH * WW)    = make_float2((float)r3.x, (float)r3.y);
}

// ---------- f32 fallback if ws is too small ----------
#define NEGINF (-INFINITY)
__global__ __launch_bounds__(192, 8) void semiconv2d_f32(
    const float* __restrict__ x, const float* __restrict__ kk, float* __restrict__ out)
{
    const int tid = threadIdx.x;
    const int w  = tid % WW;
    const int hr = tid / WW;
    const int b   = blockIdx.x;
    const int ocb = b & 7;
    const int hp  = (b >> 3) % 48;
    const int n   = (b >> 3) / 48;
    const int h   = hp * 2 + hr;
    const int oc0 = ocb * 4;
    float a0[4], a1[4], a2[4];
#pragma unroll
    for (int i = 0; i < 4; ++i) { a0[i] = NEGINF; a1[i] = NEGINF; a2[i] = NEGINF; }
    const bool vm = (h > 0), vp = (h < HH - 1);
    const int hm  = vm ? h - 1 : h;
    const int hpl = vp ? h + 1 : h;
    const int cm  = (w > 0) ? -1 : 0;
    const int cp  = (w < WW - 1) ? 1 : 0;
    const float* rm = x + ((size_t)(n * CIN) * HH + hm)  * WW + w;
    const float* r1 = x + ((size_t)(n * CIN) * HH + h)   * WW + w;
    const float* rp = x + ((size_t)(n * CIN) * HH + hpl) * WW + w;
#pragma unroll 2
    for (int ic = 0; ic < CIN; ++ic) {
        float r00 = vm ? rm[cm] : NEGINF, r01 = vm ? rm[0] : NEGINF, r02 = vm ? rm[cp] : NEGINF;
        float r10 = r1[cm], r11 = r1[0], r12 = r1[cp];
        float r20 = vp ? rp[cm] : NEGINF, r21 = vp ? rp[0] : NEGINF, r22 = vp ? rp[cp] : NEGINF;
#pragma unroll
        for (int oc = 0; oc < 4; ++oc) {
            const float* kq = kk + (size_t)(((oc0 + oc) * CIN + ic)) * 9;
            a0[oc] = fmaxf(fmaxf(a0[oc], fminf(r00, kq[0])), fmaxf(fminf(r10, kq[3]), fminf(r20, kq[6])));
            a1[oc] = fmaxf(fmaxf(a1[oc], fminf(r01, kq[1])), fmaxf(fminf(r11, kq[4]), fminf(r21, kq[7])));
            a2[oc] = fmaxf(fmaxf(a2[oc], fminf(r02, kq[2])), fmaxf(fminf(r12, kq[5]), fminf(r22, kq[8])));
        }
        rm += HH * WW; r1 += HH * WW; rp += HH * WW;
    }
#pragma unroll
    for (int oc = 0; oc < 4; ++oc) {
        float v0 = (w > 0)      ? a0[oc] : NEGINF;
        float v2 = (w < WW - 1) ? a2[oc] : NEGINF;
        out[(((size_t)(n * OCN + oc0 + oc)) * HH + h) * WW + w] = fmaxf(fmaxf(v0, a1[oc]), v2);
    }
}

extern "C" void kernel_launch(void* const* d_in, const int* in_sizes, int n_in,
                              void* d_out, int out_size, void* d_ws, size_t ws_size,
                              hipStream_t stream) {
    const float* x  = (const float*)d_in[0];
    const float* kk = (const float*)d_in[1];
    float* out      = (float*)d_out;
    if (ws_size >= WS_NEED) {
        uint2* xq   = (uint2*)d_ws;
        uint4* tblg = (uint4*)((char*)d_ws + (size_t)XQ_TOTAL * 8);
        setup_all<<<dim3(XQB + NOCG), dim3(256), 0, stream>>>(x, kk, xq, tblg);
        semiconv_g4<<<dim3(8 * NOCG * 24), dim3(192), 0, stream>>>(
            (const char*)xq, tblg, out);
    } else {
        semiconv2d_f32<<<dim3(8 * 48 * 8), dim3(192), 0, stream>>>(x, kk, out);
    }
}

// Round 3
// 89.287 us; speedup vs baseline: 1.1842x; 1.1842x over previous
//
#include <hip/hip_runtime.h>
#include <math.h>
#include <stdint.h>

// SemiConv2d tropical conv: out = max_{ic,kh,kw} min(x_pad, K). f16-packed.
// R16: COMPACT (non-redundant) xq layout, 200B rows. Post-mortems: R14
// (4x fewer loads, -2.8us) and R15 (4x fewer waves via oc-share, +7us)
// reject per-wave load count and oc-redundancy as binding. Budget model:
// timed window = ~44us ws re-poison fill (harness, 268MB @75% peak,
// irreducible) + setup ~15 + main ~40. Main sits at the L2-BYTE roofline
// (906MB dense / 35TB/s = 26us, x0.73 exit ~19; latency padding to ~40).
// R14 layout stored every pixel TWICE (384B/row) only for 8B alignment;
// dwordx2 needs just 4B (proven R13). New row = 98 f16 (w=-1..96, -inf
// pad), 200B stride: lane jj loads 8B @ 4*jj -> x[2jj-1..2jj+2]. Main L2
// bytes -33% (604MB dense), setup traffic -45% (write 4.9MB not 18.8).
// Exit reverted to R14 per-oc sorted rows (R15 isolated weak-threshold
// cost), 4 rows/iter, k-entries via uniform s_load (64B group = dwordx16),
// saddr+voffset addressing (0 VALU addr per row).
// Predict: setup 15->9, main 40->27-30, total 98.7 -> 83-88. If >=95:
// latency-bound, next = paired output rows + imm-offset load bursts.

#define HH 96
#define WW 96
#define CIN 32
#define OCN 32
#define XQ_ROWS 98
#define ROWB 200                                // bytes per padded row (98 f16 + pad)
#define SLICEB (XQ_ROWS * ROWB)                 // 19600 B per (n,ic) slice
#define XQ_BYTES ((size_t)256 * SLICEB)         // 5,017,600 B
#define ROWU2 25                                // uint2 (8B) per row
#define XQW_TOTAL (256 * XQ_ROWS * ROWU2)       // 627,200 setup threads
#define XQWB (XQW_TOTAL / 256)                  // 2450 pack blocks
#define NROW 96                                 // sorted row-entries per oc
#define TBL_BYTES ((size_t)OCN * NROW * 16)
#define RMX_BYTES ((size_t)OCN * NROW * 4)
#define WS_NEED (XQ_BYTES + TBL_BYTES + RMX_BYTES)
#define NEGH2 0xFC00FC00u

typedef _Float16 h2 __attribute__((ext_vector_type(2)));
typedef uint32_t u2a4 __attribute__((ext_vector_type(2), aligned(4)));

__device__ __forceinline__ uint32_t pkmin_vs(uint32_t x, uint32_t k) {
    uint32_t d;
    asm("v_pk_min_f16 %0, %1, %2" : "=v"(d) : "v"(x), "s"(k));
    return d;
}
__device__ __forceinline__ uint32_t pkmin_vv(uint32_t a, uint32_t b) {
    uint32_t d;
    asm("v_pk_min_f16 %0, %1, %2" : "=v"(d) : "v"(a), "v"(b));
    return d;
}
__device__ __forceinline__ uint32_t pkmax(uint32_t a, uint32_t b) {
    uint32_t d;
    asm("v_pk_max_f16 %0, %1, %2" : "=v"(d) : "v"(a), "v"(b));
    return d;
}
__device__ __forceinline__ uint32_t packh2(float lo, float hi) {
    h2 p = {(_Float16)lo, (_Float16)hi};
    return __builtin_bit_cast(uint32_t, p);
}

// Fused setup.
// Blocks [0, XQWB): pack x -> compact xq. Row (s, hp): 98 f16 covering
//   w = -1..96 at bytes 0..195 (+4B pad), value = x[s][hp-1][w] or -inf.
// Blocks [XQWB, XQWB+32): per-oc row table sorted by rowmax desc.
//   entry uint4 = {k0dup, k1dup, k2dup, byte_off of (ic,dh) row}
//   rmx[rank]  = rowmax dup (exit threshold bounds all remaining k).
__global__ __launch_bounds__(256) void setup_all(const float* __restrict__ x,
                                                 const float* __restrict__ kk,
                                                 uint2* __restrict__ xq,
                                                 uint4* __restrict__ tbl,
                                                 uint32_t* __restrict__ rmx) {
    __shared__ float rs[NROW];
    const int bb = blockIdx.x;
    if (bb < XQWB) {
        int idx = bb * 256 + threadIdx.x;       // over 256*98*25
        int j8 = idx % ROWU2;                   // 8B unit in row
        int t  = idx / ROWU2;
        int hp = t % XQ_ROWS;
        int s  = t / XQ_ROWS;
        int h  = hp - 1;
        bool hv = (h >= 0) && (h < HH);
        const float* row = x + ((size_t)s * HH + (hv ? h : 0)) * WW;
        float v[4];
#pragma unroll
        for (int q = 0; q < 4; ++q) {
            int w = 4 * j8 - 1 + q;
            v[q] = (hv && w >= 0 && w < WW) ? row[w] : -INFINITY;
        }
        uint2 o;
        o.x = packh2(v[0], v[1]);
        o.y = packh2(v[2], v[3]);
        xq[idx] = o;
        return;
    }
    // ---- table path ----
    const int oc = bb - XQWB;
    const int t  = threadIdx.x;
    if (t >= NROW) return;
    const int ic = t / 3, dh = t - 3 * ic;
    const float* kp = kk + ((size_t)(oc * CIN + ic) * 3 + dh) * 3;
    float k0 = kp[0], k1 = kp[1], k2 = kp[2];
    float rm = fmaxf(fmaxf(k0, k1), k2);
    rs[t] = rm;
    __syncthreads();
    int rank = 0;
    for (int s = 0; s < NROW; ++s) {
        float v = rs[s];
        rank += (v > rm) || (v == rm && s < t);
    }
    uint32_t off = (uint32_t)(ic * XQ_ROWS + dh) * ROWB;
    tbl[oc * NROW + rank] = make_uint4(packh2(k0, k0), packh2(k1, k1),
                                       packh2(k2, k2), off);
    rmx[oc * NROW + rank] = packh2(rm, rm);
}

__global__ __launch_bounds__(192, 8) void semiconv_c(const char* __restrict__ xqb,
                                                     const uint4* __restrict__ tbl,
                                                     const uint32_t* __restrict__ rmx,
                                                     float* __restrict__ out) {
    const int tid = threadIdx.x;
    const int jj = tid % 48;          // w-pair 0..47
    const int hr = tid / 48;          // 0..3
    const int b  = blockIdx.x;
    const int hp = b % 24;            // hp FASTEST -> XCD spread + L2 locality
    const int t  = b / 24;
    const int oc = t & 31;
    const int n  = t >> 5;
    const int h  = hp * 4 + hr;       // one output row per thread (2 w)

    const char* xqn = xqb + (size_t)n * CIN * SLICEB;   // uniform
    const int vbyte = h * ROWB + 4 * jj;                // per-lane
    const uint4* tb = tbl + oc * NROW;
    const uint32_t* rb = rmx + oc * NROW;

    uint32_t acc = NEGH2;

    for (int c = 0; c < NROW / 4; ++c) {
        // uniform scalar loads: 64B entry group (+ next-group threshold)
        uint4 e0 = tb[4 * c], e1 = tb[4 * c + 1], e2 = tb[4 * c + 2], e3 = tb[4 * c + 3];
        uint32_t kn = (c < NROW / 4 - 1) ? rb[4 * c + 4] : 0u;

        const char* r0 = xqn + e0.w;  // uniform bases -> saddr + v(vbyte)
        const char* r1 = xqn + e1.w;
        const char* r2 = xqn + e2.w;
        const char* r3 = xqn + e3.w;
        u2a4 q0 = *(const u2a4*)(r0 + vbyte);
        u2a4 q1 = *(const u2a4*)(r1 + vbyte);
        u2a4 q2 = *(const u2a4*)(r2 + vbyte);
        u2a4 q3 = *(const u2a4*)(r3 + vbyte);
        uint32_t v0 = __builtin_amdgcn_alignbit(q0.y, q0.x, 16);
        uint32_t v1 = __builtin_amdgcn_alignbit(q1.y, q1.x, 16);
        uint32_t v2 = __builtin_amdgcn_alignbit(q2.y, q2.x, 16);
        uint32_t v3 = __builtin_amdgcn_alignbit(q3.y, q3.x, 16);
        uint32_t m0 = pkmax(pkmax(pkmin_vs(q0.x, e0.x), pkmin_vs(v0, e0.y)),
                            pkmin_vs(q0.y, e0.z));
        uint32_t m1 = pkmax(pkmax(pkmin_vs(q1.x, e1.x), pkmin_vs(v1, e1.y)),
                            pkmin_vs(q1.y, e1.z));
        uint32_t m2 = pkmax(pkmax(pkmin_vs(q2.x, e2.x), pkmin_vs(v2, e2.y)),
                            pkmin_vs(q2.y, e2.z));
        uint32_t m3 = pkmax(pkmax(pkmin_vs(q3.x, e3.x), pkmin_vs(v3, e3.y)),
                            pkmin_vs(q3.y, e3.z));
        acc = pkmax(acc, pkmax(pkmax(m0, m1), pkmax(m2, m3)));

        if (c < NROW / 4 - 1) {
            // done iff min(acc.lo, acc.hi) >= next rowmax (max of remaining)
            uint32_t sw = __builtin_amdgcn_alignbit(acc, acc, 16);
            uint32_t mn = pkmin_vv(acc, sw);
            h2 a  = __builtin_bit_cast(h2, mn);
            h2 kv = __builtin_bit_cast(h2, kn);
            if (__all((float)a.x >= (float)kv.x)) break;
        }
    }

    h2 a = __builtin_bit_cast(h2, acc);
    float2 v = make_float2((float)a.x, (float)a.y);
    *(float2*)(out + (((size_t)(n * OCN + oc)) * HH + h) * WW + 2 * jj) = v;
}

// ---------- f32 fallback if ws is too small ----------
#define NEGINF (-INFINITY)
__global__ __launch_bounds__(192, 8) void semiconv2d_f32(
    const float* __restrict__ x, const float* __restrict__ kk, float* __restrict__ out)
{
    const int tid = threadIdx.x;
    const int w  = tid % WW;
    const int hr = tid / WW;
    const int b   = blockIdx.x;
    const int ocb = b & 7;
    const int hp  = (b >> 3) % 48;
    const int n   = (b >> 3) / 48;
    const int h   = hp * 2 + hr;
    const int oc0 = ocb * 4;
    float a0[4], a1[4], a2[4];
#pragma unroll
    for (int i = 0; i < 4; ++i) { a0[i] = NEGINF; a1[i] = NEGINF; a2[i] = NEGINF; }
    const bool vm = (h > 0), vp = (h < HH - 1);
    const int hm  = vm ? h - 1 : h;
    const int hpl = vp ? h + 1 : h;
    const int cm  = (w > 0) ? -1 : 0;
    const int cp  = (w < WW - 1) ? 1 : 0;
    const float* rm = x + ((size_t)(n * CIN) * HH + hm)  * WW + w;
    const float* r1 = x + ((size_t)(n * CIN) * HH + h)   * WW + w;
    const float* rp = x + ((size_t)(n * CIN) * HH + hpl) * WW + w;
#pragma unroll 2
    for (int ic = 0; ic < CIN; ++ic) {
        float r00 = vm ? rm[cm] : NEGINF, r01 = vm ? rm[0] : NEGINF, r02 = vm ? rm[cp] : NEGINF;
        float r10 = r1[cm], r11 = r1[0], r12 = r1[cp];
        float r20 = vp ? rp[cm] : NEGINF, r21 = vp ? rp[0] : NEGINF, r22 = vp ? rp[cp] : NEGINF;
#pragma unroll
        for (int oc = 0; oc < 4; ++oc) {
            const float* kq = kk + (size_t)(((oc0 + oc) * CIN + ic)) * 9;
            a0[oc] = fmaxf(fmaxf(a0[oc], fminf(r00, kq[0])), fmaxf(fminf(r10, kq[3]), fminf(r20, kq[6])));
            a1[oc] = fmaxf(fmaxf(a1[oc], fminf(r01, kq[1])), fmaxf(fminf(r11, kq[4]), fminf(r21, kq[7])));
            a2[oc] = fmaxf(fmaxf(a2[oc], fminf(r02, kq[2])), fmaxf(fminf(r12, kq[5]), fminf(r22, kq[8])));
        }
        rm += HH * WW; r1 += HH * WW; rp += HH * WW;
    }
#pragma unroll
    for (int oc = 0; oc < 4; ++oc) {
        float v0 = (w > 0)      ? a0[oc] : NEGINF;
        float v2 = (w < WW - 1) ? a2[oc] : NEGINF;
        out[(((size_t)(n * OCN + oc0 + oc)) * HH + h) * WW + w] = fmaxf(fmaxf(v0, a1[oc]), v2);
    }
}

extern "C" void kernel_launch(void* const* d_in, const int* in_sizes, int n_in,
                              void* d_out, int out_size, void* d_ws, size_t ws_size,
                              hipStream_t stream) {
    const float* x  = (const float*)d_in[0];
    const float* kk = (const float*)d_in[1];
    float* out      = (float*)d_out;
    if (ws_size >= WS_NEED) {
        uint2*    xq  = (uint2*)d_ws;
        uint4*    tbl = (uint4*)((char*)d_ws + XQ_BYTES);
        uint32_t* rmx = (uint32_t*)((char*)d_ws + XQ_BYTES + TBL_BYTES);
        setup_all<<<dim3(XQWB + OCN), dim3(256), 0, stream>>>(x, kk, xq, tbl, rmx);
        semiconv_c<<<dim3(8 * OCN * 24), dim3(192), 0, stream>>>(
            (const char*)xq, tbl, rmx, out);
    } else {
        semiconv2d_f32<<<dim3(8 * 48 * 8), dim3(192), 0, stream>>>(x, kk, out);
    }
}